// Round 1
// baseline (867.016 us; speedup 1.0000x reference)
//
#include <hip/hip_runtime.h>
#include <hip/hip_bf16.h>
#include <cstdint>
#include <cstddef>

// Problem dims (fixed)
#define B_  32
#define S_  2048
#define E_  1024
#define A_  1024
#define D_  1024
#define M_TOT (B_ * S_)     // 65536 rows of flattened [B*S, E]

typedef __attribute__((ext_vector_type(8))) __bf16 bf16x8;
typedef __attribute__((ext_vector_type(4))) float  f32x4;

__device__ __forceinline__ float fast_tanh(float x) {
    // tanh(x) = 1 - 2/(exp(2x)+1); clamp so __expf never overflows
    float cx = fminf(fmaxf(x, -15.f), 15.f);
    float e2 = __expf(2.f * cx);
    return 1.f - 2.f / (e2 + 1.f);
}

__device__ __forceinline__ bf16x8 cvt8(const float* __restrict__ p) {
    float4 f0 = *(const float4*)p;
    float4 f1 = *(const float4*)(p + 4);
    bf16x8 r;
    r[0] = (__bf16)f0.x; r[1] = (__bf16)f0.y; r[2] = (__bf16)f0.z; r[3] = (__bf16)f0.w;
    r[4] = (__bf16)f1.x; r[5] = (__bf16)f1.y; r[6] = (__bf16)f1.z; r[7] = (__bf16)f1.w;
    return r;
}

// ---------------- k0a: enc fp32 -> bf16 copy (Xb) ----------------
__global__ __launch_bounds__(256) void k_convert_enc(const float* __restrict__ enc,
                                                     __bf16* __restrict__ xb) {
    size_t idx = ((size_t)blockIdx.x * 256 + threadIdx.x) * 8;
    *(bf16x8*)(xb + idx) = cvt8(enc + idx);
}

// ---------------- k0b: U_a [k][n] -> Ut [n][k] bf16 ----------------
__global__ __launch_bounds__(256) void k_transpose_U(const float* __restrict__ Ua,
                                                     __bf16* __restrict__ Ut) {
    int idx = blockIdx.x * 256 + threadIdx.x;   // 0 .. 1048575, coalesced read
    int k = idx >> 10, n = idx & 1023;
    Ut[n * 1024 + k] = (__bf16)Ua[idx];
}

// ---------------- k1: w[b,a] = dec[b,:] . W_a[:,a]  (fp32) ----------------
__global__ __launch_bounds__(256) void k_w(const float* __restrict__ dec,
                                           const float* __restrict__ Wa,
                                           float* __restrict__ w) {
    int b = blockIdx.x >> 2;
    int a = (blockIdx.x & 3) * 256 + threadIdx.x;
    float acc = 0.f;
    #pragma unroll 8
    for (int k = 0; k < 1024; ++k)
        acc += dec[b * 1024 + k] * Wa[k * 1024 + a];   // dec: scalar-uniform, Wa: coalesced
    w[b * 1024 + a] = acc;
}

// ---------------- k2: fused e-GEMM ----------------
// e_part[n_tile][m] = sum over this block's 128 cols of  v[a]*tanh(w[b,a]+u[m,a])
// Tile: 128(M) x 128(N), K streamed in 32-chunks. 4 waves, each 64x64 (4x4 of 16x16).
// MFMA layouts (verified m89/m91): A/B frag: m|n = lane&15, k = (lane>>4)*8+j (contiguous 8)
//                                   C/D:     col = lane&15, row = (lane>>4)*4 + reg
#define LSTR 40   // 32 + 8 pad: rows stay 16B aligned, 2-way bank conflict only (free)

template <bool USE_XB>
__global__ __launch_bounds__(256) void k_gemm_e(
        const float* __restrict__ enc, const __bf16* __restrict__ Xb,
        const __bf16* __restrict__ Ut, const float* __restrict__ w,
        const float* __restrict__ v, float* __restrict__ e_part) {
    __shared__ __bf16 lX[128 * LSTR];
    __shared__ __bf16 lU[128 * LSTR];
    __shared__ float  e_lds[2][128];

    const int t      = threadIdx.x;
    const int m_tile = blockIdx.x >> 3;
    const int n_tile = blockIdx.x & 7;
    const int m0 = m_tile * 128;
    const int n0 = n_tile * 128;
    const int wave = t >> 6;
    const int lane = t & 63;
    const int q = lane >> 4;
    const int c = lane & 15;
    const int wm = (wave >> 1) * 64;   // waves (0,1): rows 0..63 ; (2,3): rows 64..127
    const int wn = (wave & 1) * 64;    // waves (0,2): cols 0..63 ; (1,3): cols 64..127

    f32x4 acc[4][4];
    #pragma unroll
    for (int i = 0; i < 4; ++i)
        #pragma unroll
        for (int j = 0; j < 4; ++j)
            #pragma unroll
            for (int r = 0; r < 4; ++r) acc[i][j][r] = 0.f;

    const int srow = t >> 2;          // 0..63
    const int scol = (t & 3) * 8;     // 0,8,16,24

    for (int kk = 0; kk < 1024; kk += 32) {
        __syncthreads();
        // stage X tile [128 x 32]
        if (USE_XB) {
            const __bf16* s0 = Xb + (size_t)(m0 + srow) * 1024 + kk + scol;
            *(int4*)(&lX[srow * LSTR + scol])        = *(const int4*)s0;
            *(int4*)(&lX[(srow + 64) * LSTR + scol]) = *(const int4*)(s0 + 64 * 1024);
        } else {
            const float* s0 = enc + (size_t)(m0 + srow) * 1024 + kk + scol;
            *(bf16x8*)(&lX[srow * LSTR + scol])        = cvt8(s0);
            *(bf16x8*)(&lX[(srow + 64) * LSTR + scol]) = cvt8(s0 + (size_t)64 * 1024);
        }
        // stage Ut tile [128 x 32] (bf16 already)
        {
            const __bf16* u0 = Ut + (size_t)(n0 + srow) * 1024 + kk + scol;
            *(int4*)(&lU[srow * LSTR + scol])        = *(const int4*)u0;
            *(int4*)(&lU[(srow + 64) * LSTR + scol]) = *(const int4*)(u0 + 64 * 1024);
        }
        __syncthreads();

        bf16x8 af[4], bfr[4];
        #pragma unroll
        for (int i = 0; i < 4; ++i)
            af[i] = *(const bf16x8*)(&lX[(wm + i * 16 + c) * LSTR + q * 8]);
        #pragma unroll
        for (int j = 0; j < 4; ++j)
            bfr[j] = *(const bf16x8*)(&lU[(wn + j * 16 + c) * LSTR + q * 8]);
        #pragma unroll
        for (int i = 0; i < 4; ++i)
            #pragma unroll
            for (int j = 0; j < 4; ++j)
                acc[i][j] = __builtin_amdgcn_mfma_f32_16x16x32_bf16(af[i], bfr[j], acc[i][j], 0, 0, 0);
    }

    // epilogue: e_row_partial = sum_cols v[col]*tanh(w[b,col] + u)
    const int b_idx = m0 >> 11;   // 2048 rows per batch, 128 | 2048
    float wv[4], vv[4];
    #pragma unroll
    for (int j = 0; j < 4; ++j) {
        int col = n0 + wn + j * 16 + c;
        wv[j] = w[b_idx * 1024 + col];
        vv[j] = v[col];
    }
    #pragma unroll
    for (int i = 0; i < 4; ++i) {
        float s0 = 0.f, s1 = 0.f, s2 = 0.f, s3 = 0.f;
        #pragma unroll
        for (int j = 0; j < 4; ++j) {
            s0 += fast_tanh(wv[j] + acc[i][j][0]) * vv[j];
            s1 += fast_tanh(wv[j] + acc[i][j][1]) * vv[j];
            s2 += fast_tanh(wv[j] + acc[i][j][2]) * vv[j];
            s3 += fast_tanh(wv[j] + acc[i][j][3]) * vv[j];
        }
        // reduce across the 16 lanes sharing q (the 16 cols of a subtile)
        #pragma unroll
        for (int off = 1; off < 16; off <<= 1) {
            s0 += __shfl_xor(s0, off, 16);
            s1 += __shfl_xor(s1, off, 16);
            s2 += __shfl_xor(s2, off, 16);
            s3 += __shfl_xor(s3, off, 16);
        }
        if (c == 0) {
            int row = wm + i * 16 + q * 4;
            e_lds[wave & 1][row + 0] = s0;
            e_lds[wave & 1][row + 1] = s1;
            e_lds[wave & 1][row + 2] = s2;
            e_lds[wave & 1][row + 3] = s3;
        }
    }
    __syncthreads();
    if (t < 128)
        e_part[(size_t)n_tile * M_TOT + m0 + t] = e_lds[0][t] + e_lds[1][t];
}

// ---------------- k3: softmax over S per batch ----------------
__global__ __launch_bounds__(256) void k_softmax(const float* __restrict__ ep,
                                                 float* __restrict__ al) {
    int b = blockIdx.x, t = threadIdx.x;
    float ev[8];
    #pragma unroll
    for (int i = 0; i < 8; ++i) {
        int s = i * 256 + t;
        float x = 0.f;
        #pragma unroll
        for (int p = 0; p < 8; ++p) x += ep[p * M_TOT + b * 2048 + s];
        ev[i] = x;
    }
    float mx = ev[0];
    #pragma unroll
    for (int i = 1; i < 8; ++i) mx = fmaxf(mx, ev[i]);
    #pragma unroll
    for (int off = 1; off < 64; off <<= 1) mx = fmaxf(mx, __shfl_xor(mx, off, 64));
    __shared__ float redm[4];
    if ((t & 63) == 0) redm[t >> 6] = mx;
    __syncthreads();
    mx = fmaxf(fmaxf(redm[0], redm[1]), fmaxf(redm[2], redm[3]));

    float ex[8], sm = 0.f;
    #pragma unroll
    for (int i = 0; i < 8; ++i) { ex[i] = __expf(ev[i] - mx); sm += ex[i]; }
    #pragma unroll
    for (int off = 1; off < 64; off <<= 1) sm += __shfl_xor(sm, off, 64);
    __shared__ float reds[4];
    if ((t & 63) == 0) reds[t >> 6] = sm;
    __syncthreads();
    sm = reds[0] + reds[1] + reds[2] + reds[3];
    float inv = 1.f / sm;
    #pragma unroll
    for (int i = 0; i < 8; ++i) al[b * 2048 + i * 256 + t] = ex[i] * inv;
}

// ---------------- k4: context partials (fp32 enc for accuracy) ----------------
// ctx_part[sc][b][e] = sum over its 256-s chunk of align[b,s]*enc[b,s,e]
__global__ __launch_bounds__(256) void k_ctx(const float* __restrict__ enc,
                                             const float* __restrict__ al,
                                             float* __restrict__ ctx_part) {
    int b  = blockIdx.x >> 3;
    int sc = blockIdx.x & 7;
    int t  = threadIdx.x;
    int e0 = t * 4;
    float ax = 0.f, ay = 0.f, az = 0.f, aw = 0.f;
    int sbase = sc * 256;
    for (int s = 0; s < 256; s += 8) {
        #pragma unroll
        for (int u = 0; u < 8; ++u) {
            int ss = sbase + s + u;
            float a = al[b * 2048 + ss];                       // uniform -> scalar load
            float4 x = *(const float4*)(enc + (size_t)(b * 2048 + ss) * 1024 + e0);
            ax += a * x.x; ay += a * x.y; az += a * x.z; aw += a * x.w;
        }
    }
    float4 r; r.x = ax; r.y = ay; r.z = az; r.w = aw;
    *(float4*)(ctx_part + (size_t)sc * (B_ * 1024) + b * 1024 + e0) = r;
}

// ---------------- k5: sum ctx partials, write context out, FFN + tanh ----------------
__global__ __launch_bounds__(256) void k_out(const float* __restrict__ dec,
                                             const float* __restrict__ ffn,
                                             const float* __restrict__ ctx_part,
                                             float* __restrict__ out) {
    int b     = blockIdx.x >> 2;
    int chunk = blockIdx.x & 3;
    int t     = threadIdx.x;
    __shared__ float ctx_l[1024];
    for (int e = t; e < 1024; e += 256) {
        float s = 0.f;
        #pragma unroll
        for (int p = 0; p < 8; ++p) s += ctx_part[(size_t)p * (B_ * 1024) + b * 1024 + e];
        ctx_l[e] = s;
        if (chunk == 0) out[32768 + b * 1024 + e] = s;   // context output
    }
    __syncthreads();
    int d = chunk * 256 + t;
    float acc = 0.f;
    #pragma unroll 8
    for (int i = 0; i < 1024; ++i)
        acc += dec[b * 1024 + i] * ffn[i * 1024 + d];
    #pragma unroll 8
    for (int e = 0; e < 1024; ++e)
        acc += ctx_l[e] * ffn[(1024 + e) * 1024 + d];
    out[b * 1024 + d] = fast_tanh(acc);                  // output
}

// ---------------- launch ----------------
extern "C" void kernel_launch(void* const* d_in, const int* in_sizes, int n_in,
                              void* d_out, int out_size, void* d_ws, size_t ws_size,
                              hipStream_t stream) {
    const float* enc = (const float*)d_in[0];
    const float* dec = (const float*)d_in[1];
    const float* Ua  = (const float*)d_in[2];
    const float* Wa  = (const float*)d_in[3];
    const float* vt  = (const float*)d_in[4];
    const float* ffn = (const float*)d_in[5];
    float* out = (float*)d_out;

    char* ws = (char*)d_ws;
    size_t off = 0;
    __bf16* Ut       = (__bf16*)(ws + off); off += (size_t)A_ * E_ * 2;           // 2 MiB
    float*  e_part   = (float*)(ws + off);  off += (size_t)8 * M_TOT * 4;         // 2 MiB
    float*  al       = (float*)(ws + off);  off += (size_t)M_TOT * 4;             // 256 KiB
    float*  wbuf     = (float*)(ws + off);  off += (size_t)B_ * A_ * 4;           // 128 KiB
    float*  ctx_part = (float*)(ws + off);  off += (size_t)8 * B_ * 1024 * 4;     // 1 MiB
    off = (off + 255) & ~(size_t)255;
    __bf16* Xb       = (__bf16*)(ws + off);
    bool use_xb = (ws_size >= off + (size_t)M_TOT * E_ * 2);                      // +128 MiB

    if (use_xb)
        k_convert_enc<<<(M_TOT * E_) / (256 * 8), 256, 0, stream>>>(enc, Xb);
    k_transpose_U<<<(E_ * A_) / 256, 256, 0, stream>>>(Ua, Ut);
    k_w<<<B_ * 4, 256, 0, stream>>>(dec, Wa, wbuf);
    if (use_xb)
        k_gemm_e<true><<<(M_TOT / 128) * 8, 256, 0, stream>>>(enc, Xb, Ut, wbuf, vt, e_part);
    else
        k_gemm_e<false><<<(M_TOT / 128) * 8, 256, 0, stream>>>(enc, Xb, Ut, wbuf, vt, e_part);
    k_softmax<<<B_, 256, 0, stream>>>(e_part, al);
    k_ctx<<<B_ * 8, 256, 0, stream>>>(enc, al, ctx_part);
    k_out<<<B_ * 4, 256, 0, stream>>>(dec, ffn, ctx_part, out);
}

// Round 2
// 712.985 us; speedup vs baseline: 1.2160x; 1.2160x over previous
//
#include <hip/hip_runtime.h>
#include <hip/hip_bf16.h>
#include <cstdint>
#include <cstddef>

// Problem dims (fixed)
#define B_  32
#define S_  2048
#define E_  1024
#define A_  1024
#define D_  1024
#define M_TOT (B_ * S_)     // 65536 rows of flattened [B*S, E]

typedef __attribute__((ext_vector_type(8))) __bf16 bf16x8;
typedef __attribute__((ext_vector_type(4))) float  f32x4;

__device__ __forceinline__ float fast_tanh(float x) {
    float cx = fminf(fmaxf(x, -15.f), 15.f);
    float e2 = __expf(2.f * cx);
    return 1.f - 2.f / (e2 + 1.f);
}

__device__ __forceinline__ bf16x8 cvt8(const float* __restrict__ p) {
    float4 f0 = *(const float4*)p;
    float4 f1 = *(const float4*)(p + 4);
    bf16x8 r;
    r[0] = (__bf16)f0.x; r[1] = (__bf16)f0.y; r[2] = (__bf16)f0.z; r[3] = (__bf16)f0.w;
    r[4] = (__bf16)f1.x; r[5] = (__bf16)f1.y; r[6] = (__bf16)f1.z; r[7] = (__bf16)f1.w;
    return r;
}

// async global->LDS, 16 B per lane; lds dest = wave-uniform base + lane*16.
// CK-style addrspace handling: low 32 bits of a generic LDS pointer are the
// LDS offset, so the integer truncation route is valid on AMDGPU.
typedef __attribute__((address_space(3))) uint32_t lds_u32_t;
typedef __attribute__((address_space(1))) const uint32_t gbl_u32_t;
__device__ __forceinline__ void async_ld16(const void* g, void* l) {
    __builtin_amdgcn_global_load_lds((gbl_u32_t*)g,
                                     (lds_u32_t*)(uint32_t)(uintptr_t)l,
                                     16, 0, 0);
}

// ---------------- k0: enc fp32 -> bf16 copy (Xb) ----------------
__global__ __launch_bounds__(256) void k_convert_enc(const float* __restrict__ enc,
                                                     __bf16* __restrict__ xb) {
    size_t idx = ((size_t)blockIdx.x * 256 + threadIdx.x) * 8;
    *(bf16x8*)(xb + idx) = cvt8(enc + idx);
}

// ---------------- k1: prep — U_a transpose (bf16) + ffn transpose (fp32) ----------------
__global__ __launch_bounds__(256) void k_prep(const float* __restrict__ Ua,
                                              __bf16* __restrict__ Ut,
                                              const float* __restrict__ ffn,
                                              float* __restrict__ ffnT) {
    int bid = blockIdx.x;
    if (bid < 4096) {                       // U: [1024k x 1024n] -> Ut[n][k]
        int idx = bid * 256 + threadIdx.x;
        int k = idx >> 10, n = idx & 1023;
        Ut[n * 1024 + k] = (__bf16)Ua[idx];
    } else {                                // ffn: [2048i x 1024d] -> ffnT[d][i]
        int idx = (bid - 4096) * 256 + threadIdx.x;
        int i = idx >> 10, d = idx & 1023;
        ffnT[(size_t)d * 2048 + i] = ffn[idx];
    }
}

// ---------------- k2: w partials, K split 8 ways ----------------
// w_part[kc][b][a] = sum_{k in kc-chunk} dec[b,k]*Wa[k,a]
__global__ __launch_bounds__(256) void k_w_part(const float* __restrict__ dec,
                                                const float* __restrict__ Wa,
                                                float* __restrict__ w_part) {
    int bid = blockIdx.x;            // 1024 = kc(8) x b(32) x ac(4)
    int ac = bid & 3, b = (bid >> 2) & 31, kc = bid >> 7;
    int a = ac * 256 + threadIdx.x;
    int k0 = kc * 128;
    float acc = 0.f;
    #pragma unroll 8
    for (int k = 0; k < 128; ++k)
        acc += dec[b * 1024 + k0 + k] * Wa[(size_t)(k0 + k) * 1024 + a];
    w_part[kc * 32768 + b * 1024 + a] = acc;
}

// ---------------- k3: fused e-GEMM (m97 structure) ----------------
// 128x128 tile, K streamed 32-wide, global_load_lds width=16 staging,
// unpadded LDS stride 32 (b128 reads are LDS-BW-floor-bound, not conflict-penalized).
// MFMA layouts (verified m89/m91): A/B frag: m|n = lane&15, k = (lane>>4)*8+j
//                                   C/D:     col = lane&15, row = (lane>>4)*4 + reg
template <bool USE_XB>
__global__ __launch_bounds__(256) void k_gemm_e(
        const float* __restrict__ enc, const __bf16* __restrict__ Xb,
        const __bf16* __restrict__ Ut, const float* __restrict__ w_part,
        const float* __restrict__ v, float* __restrict__ e_part) {
    __shared__ __bf16 lX[128 * 32];
    __shared__ __bf16 lU[128 * 32];
    __shared__ float  e_lds[2][128];

    const int t = threadIdx.x;
    // XCD swizzle: round-robin dispatch sends consecutive blocks to different
    // XCDs; keep all 8 n-tiles of one m-tile on ONE xcd so its L2 fetches the
    // 256 KB Xb tile once.  (perf heuristic only — correctness unaffected)
    const int bid = blockIdx.x;            // 0..4095
    const int xcd = bid & 7;
    const int j_  = bid >> 3;              // 0..511
    const int m_tile = xcd * 64 + (j_ >> 3);
    const int n_tile = j_ & 7;
    const int m0 = m_tile * 128;
    const int n0 = n_tile * 128;
    const int wave = t >> 6;
    const int lane = t & 63;
    const int q = lane >> 4;
    const int c = lane & 15;
    const int wm = (wave >> 1) * 64;
    const int wn = (wave & 1) * 64;

    f32x4 acc[4][4];
    #pragma unroll
    for (int i = 0; i < 4; ++i)
        #pragma unroll
        for (int j = 0; j < 4; ++j)
            #pragma unroll
            for (int r = 0; r < 4; ++r) acc[i][j][r] = 0.f;

    // async-staging lane mapping: lane covers (row = base+lane/4, col = (lane%4)*8)
    const int lrow = lane >> 2;
    const int lcol = (lane & 3) * 8;
    const int xrow = wave * 32;            // this wave stages rows [xrow, xrow+32)
    // fallback (fp32 source) mapping
    const int srow = t >> 2;
    const int scol = (t & 3) * 8;

    for (int kk = 0; kk < 1024; kk += 32) {
        __syncthreads();
        if (USE_XB) {
            const __bf16* gx = Xb + (size_t)(m0 + xrow + lrow) * 1024 + kk + lcol;
            async_ld16(gx,              &lX[(xrow     ) * 32]);
            async_ld16(gx + 16 * 1024,  &lX[(xrow + 16) * 32]);
            const __bf16* gu = Ut + (size_t)(n0 + xrow + lrow) * 1024 + kk + lcol;
            async_ld16(gu,              &lU[(xrow     ) * 32]);
            async_ld16(gu + 16 * 1024,  &lU[(xrow + 16) * 32]);
        } else {
            const float* s0 = enc + (size_t)(m0 + srow) * 1024 + kk + scol;
            *(bf16x8*)(&lX[srow * 32])        = cvt8(s0);
            *(bf16x8*)(&lX[(srow + 64) * 32]) = cvt8(s0 + (size_t)64 * 1024);
            const __bf16* u0 = Ut + (size_t)(n0 + srow) * 1024 + kk + scol;
            *(int4*)(&lU[srow * 32])        = *(const int4*)u0;
            *(int4*)(&lU[(srow + 64) * 32]) = *(const int4*)(u0 + 64 * 1024);
        }
        __syncthreads();   // emits s_waitcnt vmcnt(0) before s_barrier

        bf16x8 af[4], bfr[4];
        #pragma unroll
        for (int i = 0; i < 4; ++i)
            af[i] = *(const bf16x8*)(&lX[(wm + i * 16 + c) * 32 + q * 8]);
        #pragma unroll
        for (int j = 0; j < 4; ++j)
            bfr[j] = *(const bf16x8*)(&lU[(wn + j * 16 + c) * 32 + q * 8]);
        #pragma unroll
        for (int i = 0; i < 4; ++i)
            #pragma unroll
            for (int j = 0; j < 4; ++j)
                acc[i][j] = __builtin_amdgcn_mfma_f32_16x16x32_bf16(af[i], bfr[j], acc[i][j], 0, 0, 0);
    }

    // epilogue: e_row_partial = sum_cols v[col]*tanh(w[b,col] + u)
    const int b_idx = m0 >> 11;
    float wv[4], vv[4];
    #pragma unroll
    for (int j = 0; j < 4; ++j) {
        int col = n0 + wn + j * 16 + c;
        float s = 0.f;
        #pragma unroll
        for (int p = 0; p < 8; ++p) s += w_part[p * 32768 + b_idx * 1024 + col];
        wv[j] = s;
        vv[j] = v[col];
    }
    #pragma unroll
    for (int i = 0; i < 4; ++i) {
        float s0 = 0.f, s1 = 0.f, s2 = 0.f, s3 = 0.f;
        #pragma unroll
        for (int j = 0; j < 4; ++j) {
            s0 += fast_tanh(wv[j] + acc[i][j][0]) * vv[j];
            s1 += fast_tanh(wv[j] + acc[i][j][1]) * vv[j];
            s2 += fast_tanh(wv[j] + acc[i][j][2]) * vv[j];
            s3 += fast_tanh(wv[j] + acc[i][j][3]) * vv[j];
        }
        #pragma unroll
        for (int off = 1; off < 16; off <<= 1) {
            s0 += __shfl_xor(s0, off, 16);
            s1 += __shfl_xor(s1, off, 16);
            s2 += __shfl_xor(s2, off, 16);
            s3 += __shfl_xor(s3, off, 16);
        }
        if (c == 0) {
            int row = wm + i * 16 + q * 4;
            e_lds[wave & 1][row + 0] = s0;
            e_lds[wave & 1][row + 1] = s1;
            e_lds[wave & 1][row + 2] = s2;
            e_lds[wave & 1][row + 3] = s3;
        }
    }
    __syncthreads();
    if (t < 128)
        e_part[(size_t)n_tile * M_TOT + m0 + t] = e_lds[0][t] + e_lds[1][t];
}

// ---------------- k4: softmax over S per batch ----------------
__global__ __launch_bounds__(256) void k_softmax(const float* __restrict__ ep,
                                                 float* __restrict__ al) {
    int b = blockIdx.x, t = threadIdx.x;
    float ev[8];
    #pragma unroll
    for (int i = 0; i < 8; ++i) {
        int s = i * 256 + t;
        float x = 0.f;
        #pragma unroll
        for (int p = 0; p < 8; ++p) x += ep[p * M_TOT + b * 2048 + s];
        ev[i] = x;
    }
    float mx = ev[0];
    #pragma unroll
    for (int i = 1; i < 8; ++i) mx = fmaxf(mx, ev[i]);
    #pragma unroll
    for (int off = 1; off < 64; off <<= 1) mx = fmaxf(mx, __shfl_xor(mx, off, 64));
    __shared__ float redm[4];
    if ((t & 63) == 0) redm[t >> 6] = mx;
    __syncthreads();
    mx = fmaxf(fmaxf(redm[0], redm[1]), fmaxf(redm[2], redm[3]));

    float ex[8], sm = 0.f;
    #pragma unroll
    for (int i = 0; i < 8; ++i) { ex[i] = __expf(ev[i] - mx); sm += ex[i]; }
    #pragma unroll
    for (int off = 1; off < 64; off <<= 1) sm += __shfl_xor(sm, off, 64);
    __shared__ float reds[4];
    if ((t & 63) == 0) reds[t >> 6] = sm;
    __syncthreads();
    sm = reds[0] + reds[1] + reds[2] + reds[3];
    float inv = 1.f / sm;
    #pragma unroll
    for (int i = 0; i < 8; ++i) al[b * 2048 + i * 256 + t] = ex[i] * inv;
}

// ---------------- k5: context partials ----------------
// 64 planes: ctx_part[sc*2+sh][b][e] = sum over 32-row chunk of al*enc
template <bool USE_XB>
__global__ __launch_bounds__(256) void k_ctx(const float* __restrict__ enc,
                                             const __bf16* __restrict__ Xb,
                                             const float* __restrict__ al,
                                             float* __restrict__ ctx_part) {
    int b  = blockIdx.x >> 5;
    int sc = blockIdx.x & 31;
    int t  = threadIdx.x;
    int sh = t >> 7;
    int e8 = (t & 127) * 8;
    float acc[8];
    #pragma unroll
    for (int r = 0; r < 8; ++r) acc[r] = 0.f;
    int rbase = sc * 64 + sh * 32;
    for (int i = 0; i < 32; i += 4) {
        #pragma unroll
        for (int u = 0; u < 4; ++u) {
            int s = rbase + i + u;
            float a = al[b * 2048 + s];
            if (USE_XB) {
                bf16x8 x = *(const bf16x8*)(Xb + (size_t)(b * 2048 + s) * 1024 + e8);
                #pragma unroll
                for (int r = 0; r < 8; ++r) acc[r] += a * (float)x[r];
            } else {
                const float* xp = enc + (size_t)(b * 2048 + s) * 1024 + e8;
                float4 x0 = *(const float4*)xp;
                float4 x1 = *(const float4*)(xp + 4);
                acc[0] += a * x0.x; acc[1] += a * x0.y; acc[2] += a * x0.z; acc[3] += a * x0.w;
                acc[4] += a * x1.x; acc[5] += a * x1.y; acc[6] += a * x1.z; acc[7] += a * x1.w;
            }
        }
    }
    float* o = ctx_part + ((size_t)(sc * 2 + sh) * 32 + b) * 1024 + e8;
    float4 r0; r0.x = acc[0]; r0.y = acc[1]; r0.z = acc[2]; r0.w = acc[3];
    float4 r1; r1.x = acc[4]; r1.y = acc[5]; r1.z = acc[6]; r1.w = acc[7];
    *(float4*)o = r0;
    *(float4*)(o + 4) = r1;
}

// ---------------- k6: sum ctx partials, emit context output ----------------
__global__ __launch_bounds__(256) void k_ctx_sum(const float* __restrict__ ctx_part,
                                                 float* __restrict__ ctx,
                                                 float* __restrict__ out) {
    int idx = blockIdx.x * 256 + threadIdx.x;   // b*1024 + e
    float s = 0.f;
    #pragma unroll
    for (int p = 0; p < 64; ++p) s += ctx_part[(size_t)p * 32768 + idx];
    ctx[idx] = s;
    out[32768 + idx] = s;
}

// ---------------- k7: output GEMV — wave per (b,d) against ffnT ----------------
__global__ __launch_bounds__(256) void k_out(const float* __restrict__ dec,
                                             const float* __restrict__ ctx,
                                             const float* __restrict__ ffnT,
                                             float* __restrict__ out) {
    int b  = blockIdx.x >> 8;
    int dg = blockIdx.x & 255;
    __shared__ float cat[2048];
    int t = threadIdx.x;
    #pragma unroll
    for (int r = 0; r < 4; ++r) {
        cat[r * 256 + t]        = dec[b * 1024 + r * 256 + t];
        cat[1024 + r * 256 + t] = ctx[b * 1024 + r * 256 + t];
    }
    __syncthreads();
    int wave = t >> 6, lane = t & 63;
    int d = dg * 4 + wave;
    float acc = 0.f;
    #pragma unroll
    for (int r = 0; r < 8; ++r) {
        int idx = r * 256 + lane * 4;
        float4 c4 = *(const float4*)(cat + idx);
        float4 f4 = *(const float4*)(ffnT + (size_t)d * 2048 + idx);
        acc += c4.x * f4.x + c4.y * f4.y + c4.z * f4.z + c4.w * f4.w;
    }
    #pragma unroll
    for (int off = 1; off < 64; off <<= 1) acc += __shfl_xor(acc, off, 64);
    if (lane == 0) out[b * 1024 + d] = fast_tanh(acc);
}

// ---------------- launch ----------------
extern "C" void kernel_launch(void* const* d_in, const int* in_sizes, int n_in,
                              void* d_out, int out_size, void* d_ws, size_t ws_size,
                              hipStream_t stream) {
    const float* enc = (const float*)d_in[0];
    const float* dec = (const float*)d_in[1];
    const float* Ua  = (const float*)d_in[2];
    const float* Wa  = (const float*)d_in[3];
    const float* vt  = (const float*)d_in[4];
    const float* ffn = (const float*)d_in[5];
    float* out = (float*)d_out;

    char* ws = (char*)d_ws;
    size_t off = 0;
    __bf16* Ut       = (__bf16*)(ws + off); off += (size_t)A_ * E_ * 2;            // 2 MiB
    float*  ffnT     = (float*)(ws + off);  off += (size_t)2048 * 1024 * 4;        // 8 MiB
    float*  e_part   = (float*)(ws + off);  off += (size_t)8 * M_TOT * 4;          // 2 MiB
    float*  al       = (float*)(ws + off);  off += (size_t)M_TOT * 4;              // 256 KiB
    float*  w_part   = (float*)(ws + off);  off += (size_t)8 * B_ * 1024 * 4;      // 1 MiB
    float*  ctx_part = (float*)(ws + off);  off += (size_t)64 * B_ * 1024 * 4;     // 8 MiB
    float*  ctx      = (float*)(ws + off);  off += (size_t)B_ * 1024 * 4;          // 128 KiB
    off = (off + 255) & ~(size_t)255;
    __bf16* Xb       = (__bf16*)(ws + off);
    bool use_xb = (ws_size >= off + (size_t)M_TOT * E_ * 2);                       // +128 MiB

    if (use_xb)
        k_convert_enc<<<(M_TOT * E_) / (256 * 8), 256, 0, stream>>>(enc, Xb);
    k_prep<<<4096 + 8192, 256, 0, stream>>>(Ua, Ut, ffn, ffnT);
    k_w_part<<<1024, 256, 0, stream>>>(dec, Wa, w_part);
    if (use_xb)
        k_gemm_e<true><<<4096, 256, 0, stream>>>(enc, Xb, Ut, w_part, vt, e_part);
    else
        k_gemm_e<false><<<4096, 256, 0, stream>>>(enc, Xb, Ut, w_part, vt, e_part);
    k_softmax<<<B_, 256, 0, stream>>>(e_part, al);
    if (use_xb)
        k_ctx<true><<<B_ * 32, 256, 0, stream>>>(enc, Xb, al, ctx_part);
    else
        k_ctx<false><<<B_ * 32, 256, 0, stream>>>(enc, Xb, al, ctx_part);
    k_ctx_sum<<<(B_ * 1024) / 256, 256, 0, stream>>>(ctx_part, ctx, out);
    k_out<<<B_ * 256, 256, 0, stream>>>(dec, ctx, ffnT, out);
}

// Round 3
// 701.352 us; speedup vs baseline: 1.2362x; 1.0166x over previous
//
#include <hip/hip_runtime.h>
#include <hip/hip_bf16.h>
#include <cstdint>
#include <cstddef>

// Problem dims (fixed)
#define B_  32
#define S_  2048
#define E_  1024
#define A_  1024
#define D_  1024
#define M_TOT (B_ * S_)     // 65536 rows of flattened [B*S, E]

typedef __attribute__((ext_vector_type(8))) __bf16 bf16x8;
typedef __attribute__((ext_vector_type(4))) float  f32x4;

__device__ __forceinline__ float fast_tanh(float x) {
    float cx = fminf(fmaxf(x, -15.f), 15.f);
    float e2 = __expf(2.f * cx);
    return 1.f - 2.f / (e2 + 1.f);
}

__device__ __forceinline__ bf16x8 cvt8(const float* __restrict__ p) {
    float4 f0 = *(const float4*)p;
    float4 f1 = *(const float4*)(p + 4);
    bf16x8 r;
    r[0] = (__bf16)f0.x; r[1] = (__bf16)f0.y; r[2] = (__bf16)f0.z; r[3] = (__bf16)f0.w;
    r[4] = (__bf16)f1.x; r[5] = (__bf16)f1.y; r[6] = (__bf16)f1.z; r[7] = (__bf16)f1.w;
    return r;
}

// async global->LDS, 16 B per lane; lds dest = wave-uniform base + lane*16.
typedef __attribute__((address_space(3))) uint32_t lds_u32_t;
typedef __attribute__((address_space(1))) const uint32_t gbl_u32_t;
__device__ __forceinline__ void async_ld16(const void* g, void* l) {
    __builtin_amdgcn_global_load_lds((gbl_u32_t*)g,
                                     (lds_u32_t*)(uint32_t)(uintptr_t)l,
                                     16, 0, 0);
}

// ---------------- k0: enc fp32 -> bf16 copy (Xb) ----------------
__global__ __launch_bounds__(256) void k_convert_enc(const float* __restrict__ enc,
                                                     __bf16* __restrict__ xb) {
    size_t idx = ((size_t)blockIdx.x * 256 + threadIdx.x) * 8;
    *(bf16x8*)(xb + idx) = cvt8(enc + idx);
}

// ---------------- k1: U_a transpose via LDS tile (coalesced both sides) ----------------
__global__ __launch_bounds__(256) void k_trans_U(const float* __restrict__ Ua,
                                                 __bf16* __restrict__ Ut) {
    __shared__ float tile[64][65];          // +1 pad: conflict-free column reads
    int bid = blockIdx.x;                   // 256 = 16 k-tiles x 16 n-tiles
    int k0 = (bid >> 4) * 64, n0 = (bid & 15) * 64;
    int t = threadIdx.x;
    int r = t >> 6, c = t & 63;             // r: 0..3 (wave id), c: lane
    #pragma unroll
    for (int i = 0; i < 16; ++i)
        tile[i * 4 + r][c] = Ua[(size_t)(k0 + i * 4 + r) * 1024 + n0 + c];
    __syncthreads();
    #pragma unroll
    for (int i = 0; i < 16; ++i)
        Ut[(size_t)(n0 + i * 4 + r) * 1024 + k0 + c] = (__bf16)tile[c][i * 4 + r];
}

// ---------------- k2: w partials, K split 8 ways ----------------
__global__ __launch_bounds__(256) void k_w_part(const float* __restrict__ dec,
                                                const float* __restrict__ Wa,
                                                float* __restrict__ w_part) {
    int bid = blockIdx.x;            // 1024 = kc(8) x b(32) x ac(4)
    int ac = bid & 3, b = (bid >> 2) & 31, kc = bid >> 7;
    int a = ac * 256 + threadIdx.x;
    int k0 = kc * 128;
    float acc = 0.f;
    #pragma unroll 8
    for (int k = 0; k < 128; ++k)
        acc += dec[b * 1024 + k0 + k] * Wa[(size_t)(k0 + k) * 1024 + a];
    w_part[kc * 32768 + b * 1024 + a] = acc;
}

// ---------------- k3: fused e-GEMM — double-buffered LDS, 1 barrier/iter ----------------
// 128x128 tile, BK=32, global_load_lds width=16 staging, unpadded LDS stride 32.
// Prefetch of tile k+1 is issued BEFORE the MFMA phase on tile k, so the
// vmcnt(0) forced by __syncthreads finds the loads mostly complete.
// MFMA layouts (verified m89/m91): A/B frag: m|n = lane&15, k = (lane>>4)*8+j
//                                   C/D:     col = lane&15, row = (lane>>4)*4 + reg
template <bool USE_XB>
__global__ __launch_bounds__(256) void k_gemm_e(
        const float* __restrict__ enc, const __bf16* __restrict__ Xb,
        const __bf16* __restrict__ Ut, const float* __restrict__ w_part,
        const float* __restrict__ v, float* __restrict__ e_part) {
    __shared__ __bf16 lX[2][128 * 32];
    __shared__ __bf16 lU[2][128 * 32];
    __shared__ float  e_lds[2][128];

    const int t = threadIdx.x;
    // XCD swizzle: keep all 8 n-tiles of an m-tile on one XCD (L2 reuse).
    const int bid = blockIdx.x;            // 0..4095
    const int xcd = bid & 7;
    const int j_  = bid >> 3;              // 0..511
    const int m_tile = xcd * 64 + (j_ >> 3);
    const int n_tile = j_ & 7;
    const int m0 = m_tile * 128;
    const int n0 = n_tile * 128;
    const int wave = t >> 6;
    const int lane = t & 63;
    const int q = lane >> 4;
    const int c = lane & 15;
    const int wm = (wave >> 1) * 64;
    const int wn = (wave & 1) * 64;

    f32x4 acc[4][4];
    #pragma unroll
    for (int i = 0; i < 4; ++i)
        #pragma unroll
        for (int j = 0; j < 4; ++j)
            #pragma unroll
            for (int r = 0; r < 4; ++r) acc[i][j][r] = 0.f;

    // async-staging mapping: lane covers (row = xrow+lane/4, col = (lane%4)*8)
    const int lrow = lane >> 2;
    const int lcol = (lane & 3) * 8;
    const int xrow = wave * 32;            // this wave stages rows [xrow, xrow+32)

    if (USE_XB) {
        const __bf16* gxb = Xb + (size_t)(m0 + xrow + lrow) * 1024 + lcol;
        const __bf16* gub = Ut + (size_t)(n0 + xrow + lrow) * 1024 + lcol;

        auto stage = [&](int kk, int bsel) {
            async_ld16(gxb + kk,             &lX[bsel][xrow * 32]);
            async_ld16(gxb + kk + 16 * 1024, &lX[bsel][(xrow + 16) * 32]);
            async_ld16(gub + kk,             &lU[bsel][xrow * 32]);
            async_ld16(gub + kk + 16 * 1024, &lU[bsel][(xrow + 16) * 32]);
        };
        auto compute = [&](int bsel) {
            bf16x8 af[4], bfr[4];
            #pragma unroll
            for (int i = 0; i < 4; ++i)
                af[i] = *(const bf16x8*)(&lX[bsel][(wm + i * 16 + c) * 32 + q * 8]);
            #pragma unroll
            for (int j = 0; j < 4; ++j)
                bfr[j] = *(const bf16x8*)(&lU[bsel][(wn + j * 16 + c) * 32 + q * 8]);
            #pragma unroll
            for (int i = 0; i < 4; ++i)
                #pragma unroll
                for (int j = 0; j < 4; ++j)
                    acc[i][j] = __builtin_amdgcn_mfma_f32_16x16x32_bf16(af[i], bfr[j], acc[i][j], 0, 0, 0);
        };

        stage(0, 0);
        __syncthreads();                    // drain tile0
        for (int kk = 0; kk < 1024; kk += 64) {
            if (kk + 32 < 1024) stage(kk + 32, 1);   // prefetch next (no wait)
            compute(0);
            __syncthreads();                // drains prefetch — hidden under MFMA
            if (kk + 64 < 1024) stage(kk + 64, 0);
            compute(1);
            __syncthreads();
        }
    } else {
        // fallback: single-buffer, on-the-fly convert
        const int srow = t >> 2;
        const int scol = (t & 3) * 8;
        for (int kk = 0; kk < 1024; kk += 32) {
            __syncthreads();
            const float* s0 = enc + (size_t)(m0 + srow) * 1024 + kk + scol;
            *(bf16x8*)(&lX[0][srow * 32])        = cvt8(s0);
            *(bf16x8*)(&lX[0][(srow + 64) * 32]) = cvt8(s0 + (size_t)64 * 1024);
            const __bf16* u0 = Ut + (size_t)(n0 + srow) * 1024 + kk + scol;
            *(int4*)(&lU[0][srow * 32])        = *(const int4*)u0;
            *(int4*)(&lU[0][(srow + 64) * 32]) = *(const int4*)(u0 + 64 * 1024);
            __syncthreads();
            bf16x8 af[4], bfr[4];
            #pragma unroll
            for (int i = 0; i < 4; ++i)
                af[i] = *(const bf16x8*)(&lX[0][(wm + i * 16 + c) * 32 + q * 8]);
            #pragma unroll
            for (int j = 0; j < 4; ++j)
                bfr[j] = *(const bf16x8*)(&lU[0][(wn + j * 16 + c) * 32 + q * 8]);
            #pragma unroll
            for (int i = 0; i < 4; ++i)
                #pragma unroll
                for (int j = 0; j < 4; ++j)
                    acc[i][j] = __builtin_amdgcn_mfma_f32_16x16x32_bf16(af[i], bfr[j], acc[i][j], 0, 0, 0);
        }
    }

    // epilogue: e_row_partial = sum_cols v[col]*tanh(w[b,col] + u)
    const int b_idx = m0 >> 11;
    float wv[4], vv[4];
    #pragma unroll
    for (int j = 0; j < 4; ++j) {
        int col = n0 + wn + j * 16 + c;
        float s = 0.f;
        #pragma unroll
        for (int p = 0; p < 8; ++p) s += w_part[p * 32768 + b_idx * 1024 + col];
        wv[j] = s;
        vv[j] = v[col];
    }
    #pragma unroll
    for (int i = 0; i < 4; ++i) {
        float s0 = 0.f, s1 = 0.f, s2 = 0.f, s3 = 0.f;
        #pragma unroll
        for (int j = 0; j < 4; ++j) {
            s0 += fast_tanh(wv[j] + acc[i][j][0]) * vv[j];
            s1 += fast_tanh(wv[j] + acc[i][j][1]) * vv[j];
            s2 += fast_tanh(wv[j] + acc[i][j][2]) * vv[j];
            s3 += fast_tanh(wv[j] + acc[i][j][3]) * vv[j];
        }
        #pragma unroll
        for (int off = 1; off < 16; off <<= 1) {
            s0 += __shfl_xor(s0, off, 16);
            s1 += __shfl_xor(s1, off, 16);
            s2 += __shfl_xor(s2, off, 16);
            s3 += __shfl_xor(s3, off, 16);
        }
        if (c == 0) {
            int row = wm + i * 16 + q * 4;
            e_lds[wave & 1][row + 0] = s0;
            e_lds[wave & 1][row + 1] = s1;
            e_lds[wave & 1][row + 2] = s2;
            e_lds[wave & 1][row + 3] = s3;
        }
    }
    __syncthreads();
    if (t < 128)
        e_part[(size_t)n_tile * M_TOT + m0 + t] = e_lds[0][t] + e_lds[1][t];
}

// ---------------- k4: softmax over S per batch ----------------
__global__ __launch_bounds__(256) void k_softmax(const float* __restrict__ ep,
                                                 float* __restrict__ al) {
    int b = blockIdx.x, t = threadIdx.x;
    float ev[8];
    #pragma unroll
    for (int i = 0; i < 8; ++i) {
        int s = i * 256 + t;
        float x = 0.f;
        #pragma unroll
        for (int p = 0; p < 8; ++p) x += ep[p * M_TOT + b * 2048 + s];
        ev[i] = x;
    }
    float mx = ev[0];
    #pragma unroll
    for (int i = 1; i < 8; ++i) mx = fmaxf(mx, ev[i]);
    #pragma unroll
    for (int off = 1; off < 64; off <<= 1) mx = fmaxf(mx, __shfl_xor(mx, off, 64));
    __shared__ float redm[4];
    if ((t & 63) == 0) redm[t >> 6] = mx;
    __syncthreads();
    mx = fmaxf(fmaxf(redm[0], redm[1]), fmaxf(redm[2], redm[3]));

    float ex[8], sm = 0.f;
    #pragma unroll
    for (int i = 0; i < 8; ++i) { ex[i] = __expf(ev[i] - mx); sm += ex[i]; }
    #pragma unroll
    for (int off = 1; off < 64; off <<= 1) sm += __shfl_xor(sm, off, 64);
    __shared__ float reds[4];
    if ((t & 63) == 0) reds[t >> 6] = sm;
    __syncthreads();
    sm = reds[0] + reds[1] + reds[2] + reds[3];
    float inv = 1.f / sm;
    #pragma unroll
    for (int i = 0; i < 8; ++i) al[b * 2048 + i * 256 + t] = ex[i] * inv;
}

// ---------------- k5: context partials (bf16 enc) ----------------
template <bool USE_XB>
__global__ __launch_bounds__(256) void k_ctx(const float* __restrict__ enc,
                                             const __bf16* __restrict__ Xb,
                                             const float* __restrict__ al,
                                             float* __restrict__ ctx_part) {
    int b  = blockIdx.x >> 5;
    int sc = blockIdx.x & 31;
    int t  = threadIdx.x;
    int sh = t >> 7;
    int e8 = (t & 127) * 8;
    float acc[8];
    #pragma unroll
    for (int r = 0; r < 8; ++r) acc[r] = 0.f;
    int rbase = sc * 64 + sh * 32;
    for (int i = 0; i < 32; i += 4) {
        #pragma unroll
        for (int u = 0; u < 4; ++u) {
            int s = rbase + i + u;
            float a = al[b * 2048 + s];
            if (USE_XB) {
                bf16x8 x = *(const bf16x8*)(Xb + (size_t)(b * 2048 + s) * 1024 + e8);
                #pragma unroll
                for (int r = 0; r < 8; ++r) acc[r] += a * (float)x[r];
            } else {
                const float* xp = enc + (size_t)(b * 2048 + s) * 1024 + e8;
                float4 x0 = *(const float4*)xp;
                float4 x1 = *(const float4*)(xp + 4);
                acc[0] += a * x0.x; acc[1] += a * x0.y; acc[2] += a * x0.z; acc[3] += a * x0.w;
                acc[4] += a * x1.x; acc[5] += a * x1.y; acc[6] += a * x1.z; acc[7] += a * x1.w;
            }
        }
    }
    float* o = ctx_part + ((size_t)(sc * 2 + sh) * 32 + b) * 1024 + e8;
    float4 r0; r0.x = acc[0]; r0.y = acc[1]; r0.z = acc[2]; r0.w = acc[3];
    float4 r1; r1.x = acc[4]; r1.y = acc[5]; r1.z = acc[6]; r1.w = acc[7];
    *(float4*)o = r0;
    *(float4*)(o + 4) = r1;
}

// ---------------- k6: sum ctx partials, emit context output ----------------
__global__ __launch_bounds__(256) void k_ctx_sum(const float* __restrict__ ctx_part,
                                                 float* __restrict__ ctx,
                                                 float* __restrict__ out) {
    int idx = blockIdx.x * 256 + threadIdx.x;   // b*1024 + e
    float s = 0.f;
    #pragma unroll
    for (int p = 0; p < 64; ++p) s += ctx_part[(size_t)p * 32768 + idx];
    ctx[idx] = s;
    out[32768 + idx] = s;
}

// ---------------- k7: output GEMV partials — ffn read row-major coalesced ----------------
// out_part[kc][b][d] = sum_{i in kc*256..+255} cat[b,i] * ffn[i,d]
__global__ __launch_bounds__(256) void k_out_part(const float* __restrict__ dec,
                                                  const float* __restrict__ ctx,
                                                  const float* __restrict__ ffn,
                                                  float* __restrict__ out_part) {
    int bid = blockIdx.x;          // 256 = kc(8) x b(32)
    int b = bid & 31, kc = bid >> 5;
    int t = threadIdx.x;
    __shared__ float catl[256];
    int i0 = kc * 256;
    catl[t] = (i0 < 1024) ? dec[b * 1024 + i0 + t] : ctx[b * 1024 + i0 - 1024 + t];
    __syncthreads();
    float a0 = 0.f, a1 = 0.f, a2 = 0.f, a3 = 0.f;
    #pragma unroll 4
    for (int i = 0; i < 256; ++i) {
        float cv = catl[i];
        const float* fr = ffn + (size_t)(i0 + i) * 1024;
        a0 += cv * fr[t];
        a1 += cv * fr[t + 256];
        a2 += cv * fr[t + 512];
        a3 += cv * fr[t + 768];
    }
    float* o = out_part + ((size_t)kc * 32 + b) * 1024;
    o[t] = a0; o[t + 256] = a1; o[t + 512] = a2; o[t + 768] = a3;
}

// ---------------- k8: reduce partials + tanh ----------------
__global__ __launch_bounds__(256) void k_out_final(const float* __restrict__ out_part,
                                                   float* __restrict__ out) {
    int idx = blockIdx.x * 256 + threadIdx.x;   // 32768 = b*1024+d
    float s = 0.f;
    #pragma unroll
    for (int p = 0; p < 8; ++p) s += out_part[(size_t)p * 32768 + idx];
    out[idx] = fast_tanh(s);
}

// ---------------- launch ----------------
extern "C" void kernel_launch(void* const* d_in, const int* in_sizes, int n_in,
                              void* d_out, int out_size, void* d_ws, size_t ws_size,
                              hipStream_t stream) {
    const float* enc = (const float*)d_in[0];
    const float* dec = (const float*)d_in[1];
    const float* Ua  = (const float*)d_in[2];
    const float* Wa  = (const float*)d_in[3];
    const float* vt  = (const float*)d_in[4];
    const float* ffn = (const float*)d_in[5];
    float* out = (float*)d_out;

    char* ws = (char*)d_ws;
    size_t off = 0;
    __bf16* Ut       = (__bf16*)(ws + off); off += (size_t)A_ * E_ * 2;            // 2 MiB
    float*  e_part   = (float*)(ws + off);  off += (size_t)8 * M_TOT * 4;          // 2 MiB
    float*  al       = (float*)(ws + off);  off += (size_t)M_TOT * 4;              // 256 KiB
    float*  w_part   = (float*)(ws + off);  off += (size_t)8 * B_ * 1024 * 4;      // 1 MiB
    float*  ctx_part = (float*)(ws + off);  off += (size_t)64 * B_ * 1024 * 4;     // 8 MiB
    float*  ctx      = (float*)(ws + off);  off += (size_t)B_ * 1024 * 4;          // 128 KiB
    float*  out_part = (float*)(ws + off);  off += (size_t)8 * B_ * 1024 * 4;      // 1 MiB
    off = (off + 255) & ~(size_t)255;
    __bf16* Xb       = (__bf16*)(ws + off);
    bool use_xb = (ws_size >= off + (size_t)M_TOT * E_ * 2);                       // +128 MiB

    if (use_xb)
        k_convert_enc<<<(M_TOT * E_) / (256 * 8), 256, 0, stream>>>(enc, Xb);
    k_trans_U<<<256, 256, 0, stream>>>(Ua, Ut);
    k_w_part<<<1024, 256, 0, stream>>>(dec, Wa, w_part);
    if (use_xb)
        k_gemm_e<true><<<4096, 256, 0, stream>>>(enc, Xb, Ut, w_part, vt, e_part);
    else
        k_gemm_e<false><<<4096, 256, 0, stream>>>(enc, Xb, Ut, w_part, vt, e_part);
    k_softmax<<<B_, 256, 0, stream>>>(e_part, al);
    if (use_xb)
        k_ctx<true><<<B_ * 32, 256, 0, stream>>>(enc, Xb, al, ctx_part);
    else
        k_ctx<false><<<B_ * 32, 256, 0, stream>>>(enc, Xb, al, ctx_part);
    k_ctx_sum<<<(B_ * 1024) / 256, 256, 0, stream>>>(ctx_part, ctx, out);
    k_out_part<<<256, 256, 0, stream>>>(dec, ctx, ffn, out_part);
    k_out_final<<<(B_ * 1024) / 256, 256, 0, stream>>>(out_part, out);
}

// Round 4
// 696.194 us; speedup vs baseline: 1.2454x; 1.0074x over previous
//
#include <hip/hip_runtime.h>
#include <hip/hip_bf16.h>
#include <cstdint>
#include <cstddef>

// Problem dims (fixed)
#define B_  32
#define S_  2048
#define E_  1024
#define A_  1024
#define D_  1024
#define M_TOT (B_ * S_)     // 65536 rows of flattened [B*S, E]

typedef __attribute__((ext_vector_type(8))) __bf16 bf16x8;
typedef __attribute__((ext_vector_type(4))) float  f32x4;

__device__ __forceinline__ float fast_tanh(float x) {
    float cx = fminf(fmaxf(x, -15.f), 15.f);
    float e2 = __expf(2.f * cx);
    return 1.f - 2.f / (e2 + 1.f);
}

__device__ __forceinline__ bf16x8 pack8(float4 f0, float4 f1) {
    bf16x8 r;
    r[0] = (__bf16)f0.x; r[1] = (__bf16)f0.y; r[2] = (__bf16)f0.z; r[3] = (__bf16)f0.w;
    r[4] = (__bf16)f1.x; r[5] = (__bf16)f1.y; r[6] = (__bf16)f1.z; r[7] = (__bf16)f1.w;
    return r;
}

// async global->LDS, 16 B per lane; lds dest = wave-uniform base + lane*16.
typedef __attribute__((address_space(3))) uint32_t lds_u32_t;
typedef __attribute__((address_space(1))) const uint32_t gbl_u32_t;
__device__ __forceinline__ void async_ld16(const void* g, void* l) {
    __builtin_amdgcn_global_load_lds((gbl_u32_t*)g,
                                     (lds_u32_t*)(uint32_t)(uintptr_t)l,
                                     16, 0, 0);
}

// ---------------- k1: U_a transpose via LDS tile (coalesced both sides) ----------------
__global__ __launch_bounds__(256) void k_trans_U(const float* __restrict__ Ua,
                                                 __bf16* __restrict__ Ut) {
    __shared__ float tile[64][65];          // +1 pad: conflict-free column reads
    int bid = blockIdx.x;                   // 256 = 16 k-tiles x 16 n-tiles
    int k0 = (bid >> 4) * 64, n0 = (bid & 15) * 64;
    int t = threadIdx.x;
    int r = t >> 6, c = t & 63;             // r: 0..3 (wave id), c: lane
    #pragma unroll
    for (int i = 0; i < 16; ++i)
        tile[i * 4 + r][c] = Ua[(size_t)(k0 + i * 4 + r) * 1024 + n0 + c];
    __syncthreads();
    #pragma unroll
    for (int i = 0; i < 16; ++i)
        Ut[(size_t)(n0 + i * 4 + r) * 1024 + k0 + c] = (__bf16)tile[c][i * 4 + r];
}

// ---------------- k2: w partials, K split 8 ways ----------------
__global__ __launch_bounds__(256) void k_w_part(const float* __restrict__ dec,
                                                const float* __restrict__ Wa,
                                                float* __restrict__ w_part) {
    int bid = blockIdx.x;            // 1024 = kc(8) x b(32) x ac(4)
    int ac = bid & 3, b = (bid >> 2) & 31, kc = bid >> 7;
    int a = ac * 256 + threadIdx.x;
    int k0 = kc * 128;
    float acc = 0.f;
    #pragma unroll 8
    for (int k = 0; k < 128; ++k)
        acc += dec[b * 1024 + k0 + k] * Wa[(size_t)(k0 + k) * 1024 + a];
    w_part[kc * 32768 + b * 1024 + a] = acc;
}

// ---------------- k3: fused e-GEMM — on-the-fly fp32->bf16 A, async bf16 B ----------------
// 128x128 tile, BK=32, double-buffered LDS, 1 barrier/iter.
// A: enc fp32 -> VGPR (4x dwordx4) -> cvt -> ds_write_b128 (issued first so the
//    compiler can wait A with vmcnt(2) without draining the async-B loads).
// B: Ut bf16 via global_load_lds width=16.
// MFMA layouts (verified m89/m91): A/B frag: m|n = lane&15, k = (lane>>4)*8+j
//                                   C/D:     col = lane&15, row = (lane>>4)*4 + reg
__global__ __launch_bounds__(256) void k_gemm_e(
        const float* __restrict__ enc, const __bf16* __restrict__ Ut,
        const float* __restrict__ w_part, const float* __restrict__ v,
        float* __restrict__ e_part) {
    __shared__ __bf16 lX[2][128 * 32];
    __shared__ __bf16 lU[2][128 * 32];
    __shared__ float  e_lds[2][128];

    const int t = threadIdx.x;
    // XCD swizzle: keep all 8 n-tiles of an m-tile on one XCD (L2 reuse).
    const int bid = blockIdx.x;            // 0..4095
    const int xcd = bid & 7;
    const int j_  = bid >> 3;              // 0..511
    const int m_tile = xcd * 64 + (j_ >> 3);
    const int n_tile = j_ & 7;
    const int m0 = m_tile * 128;
    const int n0 = n_tile * 128;
    const int wave = t >> 6;
    const int lane = t & 63;
    const int q = lane >> 4;
    const int c = lane & 15;
    const int wm = (wave >> 1) * 64;
    const int wn = (wave & 1) * 64;

    f32x4 acc[4][4];
    #pragma unroll
    for (int i = 0; i < 4; ++i)
        #pragma unroll
        for (int j = 0; j < 4; ++j)
            #pragma unroll
            for (int r = 0; r < 4; ++r) acc[i][j][r] = 0.f;

    // staging mapping: wave covers rows [xrow, xrow+32); lane -> (row=xrow+lrow(+16), col=lcol..lcol+7)
    const int lrow = lane >> 2;
    const int lcol = (lane & 3) * 8;
    const int xrow = wave * 32;

    const float*  gxa = enc + (size_t)(m0 + xrow + lrow) * 1024 + lcol;
    const __bf16* gub = Ut  + (size_t)(n0 + xrow + lrow) * 1024 + lcol;

    float4 f0, f1, f2, f3;
    auto loadA = [&](int kk) {
        const float* p = gxa + kk;
        f0 = *(const float4*)p;
        f1 = *(const float4*)(p + 4);
        f2 = *(const float4*)(p + 16 * 1024);
        f3 = *(const float4*)(p + 16 * 1024 + 4);
    };
    auto writeA = [&](int bsel) {
        *(bf16x8*)(&lX[bsel][(xrow + lrow) * 32 + lcol])      = pack8(f0, f1);
        *(bf16x8*)(&lX[bsel][(xrow + 16 + lrow) * 32 + lcol]) = pack8(f2, f3);
    };
    auto stageB = [&](int kk, int bsel) {
        async_ld16(gub + kk,             &lU[bsel][xrow * 32]);
        async_ld16(gub + kk + 16 * 1024, &lU[bsel][(xrow + 16) * 32]);
    };
    auto compute = [&](int bsel) {
        bf16x8 af[4], bfr[4];
        #pragma unroll
        for (int i = 0; i < 4; ++i)
            af[i] = *(const bf16x8*)(&lX[bsel][(wm + i * 16 + c) * 32 + q * 8]);
        #pragma unroll
        for (int j = 0; j < 4; ++j)
            bfr[j] = *(const bf16x8*)(&lU[bsel][(wn + j * 16 + c) * 32 + q * 8]);
        #pragma unroll
        for (int i = 0; i < 4; ++i)
            #pragma unroll
            for (int j = 0; j < 4; ++j)
                acc[i][j] = __builtin_amdgcn_mfma_f32_16x16x32_bf16(af[i], bfr[j], acc[i][j], 0, 0, 0);
    };

    // prologue: tile 0 into buffer 0
    loadA(0);
    stageB(0, 0);
    writeA(0);
    __syncthreads();

    for (int kk = 0; kk < 1024; kk += 64) {
        if (kk + 32 < 1024) { loadA(kk + 32); stageB(kk + 32, 1); }
        compute(0);
        if (kk + 32 < 1024) writeA(1);
        __syncthreads();
        if (kk + 64 < 1024) { loadA(kk + 64); stageB(kk + 64, 0); }
        compute(1);
        if (kk + 64 < 1024) writeA(0);
        __syncthreads();
    }

    // epilogue: e_row_partial = sum_cols v[col]*tanh(w[b,col] + u)
    const int b_idx = m0 >> 11;
    float wv[4], vv[4];
    #pragma unroll
    for (int j = 0; j < 4; ++j) {
        int col = n0 + wn + j * 16 + c;
        float s = 0.f;
        #pragma unroll
        for (int p = 0; p < 8; ++p) s += w_part[p * 32768 + b_idx * 1024 + col];
        wv[j] = s;
        vv[j] = v[col];
    }
    #pragma unroll
    for (int i = 0; i < 4; ++i) {
        float s0 = 0.f, s1 = 0.f, s2 = 0.f, s3 = 0.f;
        #pragma unroll
        for (int j = 0; j < 4; ++j) {
            s0 += fast_tanh(wv[j] + acc[i][j][0]) * vv[j];
            s1 += fast_tanh(wv[j] + acc[i][j][1]) * vv[j];
            s2 += fast_tanh(wv[j] + acc[i][j][2]) * vv[j];
            s3 += fast_tanh(wv[j] + acc[i][j][3]) * vv[j];
        }
        #pragma unroll
        for (int off = 1; off < 16; off <<= 1) {
            s0 += __shfl_xor(s0, off, 16);
            s1 += __shfl_xor(s1, off, 16);
            s2 += __shfl_xor(s2, off, 16);
            s3 += __shfl_xor(s3, off, 16);
        }
        if (c == 0) {
            int row = wm + i * 16 + q * 4;
            e_lds[wave & 1][row + 0] = s0;
            e_lds[wave & 1][row + 1] = s1;
            e_lds[wave & 1][row + 2] = s2;
            e_lds[wave & 1][row + 3] = s3;
        }
    }
    __syncthreads();
    if (t < 128)
        e_part[(size_t)n_tile * M_TOT + m0 + t] = e_lds[0][t] + e_lds[1][t];
}

// ---------------- k4: softmax over S per batch ----------------
__global__ __launch_bounds__(256) void k_softmax(const float* __restrict__ ep,
                                                 float* __restrict__ al) {
    int b = blockIdx.x, t = threadIdx.x;
    float ev[8];
    #pragma unroll
    for (int i = 0; i < 8; ++i) {
        int s = i * 256 + t;
        float x = 0.f;
        #pragma unroll
        for (int p = 0; p < 8; ++p) x += ep[p * M_TOT + b * 2048 + s];
        ev[i] = x;
    }
    float mx = ev[0];
    #pragma unroll
    for (int i = 1; i < 8; ++i) mx = fmaxf(mx, ev[i]);
    #pragma unroll
    for (int off = 1; off < 64; off <<= 1) mx = fmaxf(mx, __shfl_xor(mx, off, 64));
    __shared__ float redm[4];
    if ((t & 63) == 0) redm[t >> 6] = mx;
    __syncthreads();
    mx = fmaxf(fmaxf(redm[0], redm[1]), fmaxf(redm[2], redm[3]));

    float ex[8], sm = 0.f;
    #pragma unroll
    for (int i = 0; i < 8; ++i) { ex[i] = __expf(ev[i] - mx); sm += ex[i]; }
    #pragma unroll
    for (int off = 1; off < 64; off <<= 1) sm += __shfl_xor(sm, off, 64);
    __shared__ float reds[4];
    if ((t & 63) == 0) reds[t >> 6] = sm;
    __syncthreads();
    sm = reds[0] + reds[1] + reds[2] + reds[3];
    float inv = 1.f / sm;
    #pragma unroll
    for (int i = 0; i < 8; ++i) al[b * 2048 + i * 256 + t] = ex[i] * inv;
}

// ---------------- k5: context partials (fp32 enc) ----------------
// ctx_part[sc][b][e] = sum over 64-row chunk sc of al[b,s]*enc[b,s,e]
__global__ __launch_bounds__(256) void k_ctx(const float* __restrict__ enc,
                                             const float* __restrict__ al,
                                             float* __restrict__ ctx_part) {
    int b  = blockIdx.x >> 5;
    int sc = blockIdx.x & 31;
    int t  = threadIdx.x;
    int e4 = t * 4;
    float ax = 0.f, ay = 0.f, az = 0.f, aw = 0.f;
    int sbase = sc * 64;
    for (int i = 0; i < 64; i += 4) {
        #pragma unroll
        for (int u = 0; u < 4; ++u) {
            int s = sbase + i + u;
            float a = al[b * 2048 + s];
            float4 x = *(const float4*)(enc + (size_t)(b * 2048 + s) * 1024 + e4);
            ax += a * x.x; ay += a * x.y; az += a * x.z; aw += a * x.w;
        }
    }
    float4 r; r.x = ax; r.y = ay; r.z = az; r.w = aw;
    *(float4*)(ctx_part + ((size_t)sc * 32 + b) * 1024 + e4) = r;
}

// ---------------- k6: final — ctx reduce + context out + FFN GEMV + tanh ----------------
// grid 512 = b(32) x dc(16); block handles 64 output dims, full K=2048.
__global__ __launch_bounds__(256) void k_final(const float* __restrict__ dec,
                                               const float* __restrict__ ffn,
                                               const float* __restrict__ ctx_part,
                                               float* __restrict__ out) {
    int b  = blockIdx.x >> 4;
    int dc = blockIdx.x & 15;
    int t  = threadIdx.x;
    __shared__ float cat[2048];
    __shared__ float red[4][64];

    // build cat = [dec(1024) | ctx(1024)] in LDS; ctx = sum of 32 partial planes
    #pragma unroll
    for (int r = 0; r < 4; ++r) {
        int e = r * 256 + t;
        cat[e] = dec[b * 1024 + e];
        float s = 0.f;
        #pragma unroll
        for (int p = 0; p < 32; ++p) s += ctx_part[((size_t)p * 32 + b) * 1024 + e];
        cat[1024 + e] = s;
        if (dc == 0) out[32768 + b * 1024 + e] = s;   // context output
    }
    __syncthreads();

    int dl = t & 63, ic = t >> 6;                     // d-lane, i-chunk
    int d  = dc * 64 + dl;
    float acc = 0.f;
    int i0 = ic * 512;
    for (int i = 0; i < 512; i += 4) {
        float4 cv = *(const float4*)(cat + i0 + i);   // broadcast ds_read_b128
        const float* fr = ffn + (size_t)(i0 + i) * 1024 + d;
        acc += cv.x * fr[0];
        acc += cv.y * fr[1024];
        acc += cv.z * fr[2048];
        acc += cv.w * fr[3072];
    }
    red[ic][dl] = acc;
    __syncthreads();
    if (t < 64) {
        float s = red[0][t] + red[1][t] + red[2][t] + red[3][t];
        out[b * 1024 + dc * 64 + t] = fast_tanh(s);
    }
}

// ---------------- launch ----------------
extern "C" void kernel_launch(void* const* d_in, const int* in_sizes, int n_in,
                              void* d_out, int out_size, void* d_ws, size_t ws_size,
                              hipStream_t stream) {
    const float* enc = (const float*)d_in[0];
    const float* dec = (const float*)d_in[1];
    const float* Ua  = (const float*)d_in[2];
    const float* Wa  = (const float*)d_in[3];
    const float* vt  = (const float*)d_in[4];
    const float* ffn = (const float*)d_in[5];
    float* out = (float*)d_out;

    char* ws = (char*)d_ws;
    size_t off = 0;
    __bf16* Ut       = (__bf16*)(ws + off); off += (size_t)A_ * E_ * 2;            // 2 MiB
    float*  e_part   = (float*)(ws + off);  off += (size_t)8 * M_TOT * 4;          // 2 MiB
    float*  al       = (float*)(ws + off);  off += (size_t)M_TOT * 4;              // 256 KiB
    float*  w_part   = (float*)(ws + off);  off += (size_t)8 * B_ * 1024 * 4;      // 1 MiB
    float*  ctx_part = (float*)(ws + off);  off += (size_t)32 * B_ * 1024 * 4;     // 4 MiB

    k_trans_U<<<256, 256, 0, stream>>>(Ua, Ut);
    k_w_part<<<1024, 256, 0, stream>>>(dec, Wa, w_part);
    k_gemm_e<<<4096, 256, 0, stream>>>(enc, Ut, w_part, vt, e_part);
    k_softmax<<<B_, 256, 0, stream>>>(e_part, al);
    k_ctx<<<B_ * 32, 256, 0, stream>>>(enc, al, ctx_part);
    k_final<<<B_ * 16, 256, 0, stream>>>(dec, ffn, ctx_part, out);
}